// Round 2
// baseline (2934.848 us; speedup 1.0000x reference)
//
#include <hip/hip_runtime.h>
#include <hip/hip_bf16.h>

#define NN 50000
#define NE 800000
#define NG 256

typedef __hip_bfloat16 bf16;
__device__ __forceinline__ float b2f(bf16 v) { return __bfloat162float(v); }

// ---------------- CSR build ----------------
__global__ void k_zero_i32(int* __restrict__ p, int n) {
  int i = blockIdx.x * blockDim.x + threadIdx.x;
  if (i < n) p[i] = 0;
}
__global__ void k_zero_f32(float* __restrict__ p, int n) {
  int i = blockIdx.x * blockDim.x + threadIdx.x;
  if (i < n) p[i] = 0.f;
}
__global__ void k_count(const int* __restrict__ dst, int* __restrict__ counts, int E) {
  int e = blockIdx.x * blockDim.x + threadIdx.x;
  if (e < E) atomicAdd(&counts[dst[e]], 1);
}
__global__ void k_dinv(const int* __restrict__ counts, float* __restrict__ dinv,
                       float* __restrict__ selfc, int n) {
  int i = blockIdx.x * blockDim.x + threadIdx.x;
  if (i < n) {
    float d = (float)counts[i] + 1.0f;   // +1 self loop
    dinv[i]  = rsqrtf(d);
    selfc[i] = 1.0f / d;                 // dinv^2
  }
}
// single-block exclusive scan
__global__ void k_scan(const int* __restrict__ counts, int* __restrict__ row_ptr,
                       int* __restrict__ fill, int n) {
  __shared__ int wsum[16];
  __shared__ int carry_s;
  int tid = threadIdx.x;
  if (tid == 0) carry_s = 0;
  __syncthreads();
  for (int base = 0; base < n; base += 1024) {
    int i = base + tid;
    int v = (i < n) ? counts[i] : 0;
    int incl = v;
    #pragma unroll
    for (int off = 1; off < 64; off <<= 1) {
      int t = __shfl_up(incl, off, 64);
      if ((tid & 63) >= off) incl += t;
    }
    int wid = tid >> 6;
    if ((tid & 63) == 63) wsum[wid] = incl;
    __syncthreads();
    if (tid < 16) {
      int s = wsum[tid];
      #pragma unroll
      for (int off = 1; off < 16; off <<= 1) {
        int t = __shfl_up(s, off, 16);
        if (tid >= off) s += t;
      }
      wsum[tid] = s;
    }
    __syncthreads();
    int waveoff = (wid == 0) ? 0 : wsum[wid - 1];
    int carry = carry_s;
    int excl = carry + waveoff + incl - v;
    if (i < n) { row_ptr[i] = excl; fill[i] = 0; }
    if (i == n - 1) row_ptr[n] = excl + v;
    __syncthreads();
    if (tid == 0) carry_s = carry + wsum[15];
    __syncthreads();
  }
}
__global__ void k_fill(const int* __restrict__ src, const int* __restrict__ dst,
                       const int* __restrict__ row_ptr, int* __restrict__ fill,
                       const float* __restrict__ dinv, int* __restrict__ csr_src,
                       float* __restrict__ csr_coef, int E) {
  int e = blockIdx.x * blockDim.x + threadIdx.x;
  if (e < E) {
    int s = src[e], d = dst[e];
    int pos = row_ptr[d] + atomicAdd(&fill[d], 1);
    csr_src[pos]  = s;
    csr_coef[pos] = dinv[s] * dinv[d];
  }
}

// ---------------- layer-1 aggregation of x (19 feats, padded to 32) ----------------
__global__ __launch_bounds__(256) void k_agg_x(
    const float* __restrict__ x, const int* __restrict__ row_ptr,
    const int* __restrict__ csr_src, const float* __restrict__ csr_coef,
    const float* __restrict__ selfc, float* __restrict__ aggx, int n) {
  int tid  = threadIdx.x;
  int node = blockIdx.x * 8 + (tid >> 5);
  int lane = tid & 31;
  if (node >= n) return;
  float acc = 0.f;
  if (lane < 19) {
    int e0 = row_ptr[node], e1 = row_ptr[node + 1];
    for (int e = e0; e < e1; e++)
      acc += csr_coef[e] * x[csr_src[e] * 19 + lane];
    acc += selfc[node] * x[node * 19 + lane];
  }
  aggx[node * 32 + lane] = (lane < 19) ? acc : 0.f;
}

// ---- fused layer1+2 linear: T2 = relu(aggx@W1+b1) @ W2, H1 tile stays in LDS ----
// 16 rows/block, grid = NN/16 = 3125 (exact)
__global__ __launch_bounds__(256) void k_fused12(
    const float* __restrict__ aggx, const float* __restrict__ W1,
    const float* __restrict__ b1, const float* __restrict__ W2,
    bf16* __restrict__ T2) {
  __shared__ float As[16][32];    // 2 KB
  __shared__ float Hs[16][512];   // 32 KB (cols 500..511 zero)
  __shared__ float Ws[16][416];   // 26.6 KB (cols 400..415 zero)
  int tid = threadIdx.x;
  int gr0 = blockIdx.x * 16;
  for (int i = tid; i < 512; i += 256)
    As[i >> 5][i & 31] = aggx[(size_t)(gr0 + (i >> 5)) * 32 + (i & 31)];
  __syncthreads();
  // phase A: Hs = relu(As @ W1 + b1)
  for (int i = tid; i < 16 * 512; i += 256) {
    int r = i >> 9, c = i & 511;
    float v = 0.f;
    if (c < 500) {
      float acc = b1[c];
      #pragma unroll
      for (int k = 0; k < 19; k++) acc += As[r][k] * W1[k * 500 + c];
      v = fmaxf(acc, 0.f);
    }
    Hs[r][c] = v;
  }
  // phase B: T2 = Hs @ W2 (K padded to 512 with zeros)
  int ty = tid >> 5, tx = tid & 31;
  float acc0[13], acc1[13];
  #pragma unroll
  for (int j = 0; j < 13; j++) { acc0[j] = 0.f; acc1[j] = 0.f; }
  for (int k0 = 0; k0 < 512; k0 += 16) {
    __syncthreads();
    for (int i = tid; i < 16 * 416; i += 256) {
      int kk = i / 416, c = i - kk * 416;
      int k = k0 + kk;
      float v = 0.f;
      if (c < 400 && k < 500) v = W2[(size_t)k * 400 + c];
      Ws[kk][c] = v;
    }
    __syncthreads();
    #pragma unroll
    for (int kk = 0; kk < 16; kk++) {
      float a0 = Hs[ty][k0 + kk];
      float a1 = Hs[ty + 8][k0 + kk];
      #pragma unroll
      for (int j = 0; j < 13; j++) {
        float w = Ws[kk][tx + 32 * j];
        acc0[j] += a0 * w;
        acc1[j] += a1 * w;
      }
    }
  }
  #pragma unroll
  for (int j = 0; j < 13; j++) {
    int c = tx + 32 * j;
    if (c < 400) {
      T2[(size_t)(gr0 + ty) * 400 + c]     = __float2bfloat16(acc0[j]);
      T2[(size_t)(gr0 + ty + 8) * 400 + c] = __float2bfloat16(acc1[j]);
    }
  }
}

// ---- fused layer2 agg + layer3 linear: T3 = relu(agg(T2)+b2) @ W3 ----
__global__ __launch_bounds__(256) void k_fused23(
    const bf16* __restrict__ T2, const int* __restrict__ row_ptr,
    const int* __restrict__ csr_src, const float* __restrict__ csr_coef,
    const float* __restrict__ selfc, const float* __restrict__ b2,
    const float* __restrict__ W3, bf16* __restrict__ T3) {
  __shared__ float Hs[16][400];   // 25.6 KB
  __shared__ float Ws[16][320];   // 20.5 KB (cols 300..319 zero)
  int tid = threadIdx.x;
  int gr0 = blockIdx.x * 16;
  {
    int r = tid >> 4, tx = tid & 15;
    int node = gr0 + r;
    float acc[25];
    #pragma unroll
    for (int j = 0; j < 25; j++) acc[j] = 0.f;
    int e0 = row_ptr[node], e1 = row_ptr[node + 1];
    for (int e = e0; e < e1; e++) {
      int s = csr_src[e];
      float cf = csr_coef[e];
      const bf16* rp = T2 + (size_t)s * 400;
      #pragma unroll
      for (int j = 0; j < 25; j++)
        acc[j] += cf * b2f(rp[tx + 16 * j]);
    }
    float sc = selfc[node];
    const bf16* rp = T2 + (size_t)node * 400;
    #pragma unroll
    for (int j = 0; j < 25; j++) {
      int c = tx + 16 * j;
      float v = acc[j] + sc * b2f(rp[c]) + b2[c];
      Hs[r][c] = fmaxf(v, 0.f);
    }
  }
  // phase B: T3 = Hs @ W3 (K=400, N=300 padded to 320)
  int ty = tid >> 5, tx = tid & 31;
  float acc0[10], acc1[10];
  #pragma unroll
  for (int j = 0; j < 10; j++) { acc0[j] = 0.f; acc1[j] = 0.f; }
  for (int k0 = 0; k0 < 400; k0 += 16) {
    __syncthreads();
    for (int i = tid; i < 16 * 320; i += 256) {
      int kk = i / 320, c = i - kk * 320;
      float v = 0.f;
      if (c < 300) v = W3[(size_t)(k0 + kk) * 300 + c];
      Ws[kk][c] = v;
    }
    __syncthreads();
    #pragma unroll
    for (int kk = 0; kk < 16; kk++) {
      float a0 = Hs[ty][k0 + kk];
      float a1 = Hs[ty + 8][k0 + kk];
      #pragma unroll
      for (int j = 0; j < 10; j++) {
        float w = Ws[kk][tx + 32 * j];
        acc0[j] += a0 * w;
        acc1[j] += a1 * w;
      }
    }
  }
  #pragma unroll
  for (int j = 0; j < 10; j++) {
    int c = tx + 32 * j;
    if (c < 300) {
      T3[(size_t)(gr0 + ty) * 300 + c]     = __float2bfloat16(acc0[j]);
      T3[(size_t)(gr0 + ty + 8) * 300 + c] = __float2bfloat16(acc1[j]);
    }
  }
}

// ---- fused layer3 agg + bias + relu + per-graph atomic max pool ----
__global__ __launch_bounds__(256) void k_fused3m(
    const bf16* __restrict__ T3, const int* __restrict__ row_ptr,
    const int* __restrict__ csr_src, const float* __restrict__ csr_coef,
    const float* __restrict__ selfc, const float* __restrict__ b3,
    const int* __restrict__ batch, float* __restrict__ gbuf) {
  int tid = threadIdx.x;
  int gr0 = blockIdx.x * 16;
  int r = tid >> 4, tx = tid & 15;
  int node = gr0 + r;
  float acc[19];
  #pragma unroll
  for (int j = 0; j < 19; j++) acc[j] = 0.f;
  int e0 = row_ptr[node], e1 = row_ptr[node + 1];
  for (int e = e0; e < e1; e++) {
    int s = csr_src[e];
    float cf = csr_coef[e];
    const bf16* rp = T3 + (size_t)s * 300;
    #pragma unroll
    for (int j = 0; j < 19; j++) {
      int c = tx + 16 * j;
      if (c < 300) acc[j] += cf * b2f(rp[c]);
    }
  }
  float sc = selfc[node];
  const bf16* rp = T3 + (size_t)node * 300;
  int gi = batch[node];
  #pragma unroll
  for (int j = 0; j < 19; j++) {
    int c = tx + 16 * j;
    if (c < 300) {
      float v = fmaxf(acc[j] + sc * b2f(rp[c]) + b3[c], 0.f);
      atomicMax((unsigned int*)&gbuf[(size_t)gi * 300 + c], __float_as_uint(v));
    }
  }
}

// ---------------- small dense head ----------------
__global__ void k_linear(const float* __restrict__ A, const float* __restrict__ W,
                         const float* __restrict__ b, float* __restrict__ C,
                         int M, int N, int K, int relu) {
  int idx = blockIdx.x * blockDim.x + threadIdx.x;
  if (idx >= M * N) return;
  int m = idx / N, n = idx - m * N;
  float acc = b[n];
  for (int k = 0; k < K; k++) acc += A[m * K + k] * W[k * N + n];
  if (relu) acc = fmaxf(acc, 0.f);
  C[idx] = acc;
}

// softmax over graph axis (dim 0), logits [256, 6]
__global__ void k_softmax0(const float* __restrict__ logits, float* __restrict__ out) {
  __shared__ float cmax[6], csum[6];
  int g = threadIdx.x;
  if (g < 6) {
    float m = -1e30f;
    for (int i = 0; i < NG; i++) m = fmaxf(m, logits[i * 6 + g]);
    float s = 0.f;
    for (int i = 0; i < NG; i++) s += expf(logits[i * 6 + g] - m);
    cmax[g] = m; csum[g] = s;
  }
  __syncthreads();
  for (int c = 0; c < 6; c++)
    out[g * 6 + c] = expf(logits[g * 6 + c] - cmax[c]) / csum[c];
}

extern "C" void kernel_launch(void* const* d_in, const int* in_sizes, int n_in,
                              void* d_out, int out_size, void* d_ws, size_t ws_size,
                              hipStream_t stream) {
  const float* x    = (const float*)d_in[0];
  const int*   eidx = (const int*)d_in[1];
  const int*   batch= (const int*)d_in[2];
  const float* W1 = (const float*)d_in[3];  const float* b1 = (const float*)d_in[4];
  const float* W2 = (const float*)d_in[5];  const float* b2 = (const float*)d_in[6];
  const float* W3 = (const float*)d_in[7];  const float* b3 = (const float*)d_in[8];
  const float* Wl1= (const float*)d_in[9];  const float* bl1= (const float*)d_in[10];
  const float* Wl2= (const float*)d_in[11]; const float* bl2= (const float*)d_in[12];
  const float* Wl3= (const float*)d_in[13]; const float* bl3= (const float*)d_in[14];
  const int* srcA = eidx;
  const int* dstA = eidx + NE;

  char* ws = (char*)d_ws;
  size_t off = 0;
  auto alloc = [&](size_t bytes) -> char* {
    char* p = ws + off;
    off = (off + bytes + 255) & ~(size_t)255;
    return p;
  };
  int*   counts  = (int*)  alloc((size_t)NN * 4);
  int*   row_ptr = (int*)  alloc((size_t)(NN + 1) * 4);
  int*   fill    = (int*)  alloc((size_t)NN * 4);
  float* dinv    = (float*)alloc((size_t)NN * 4);
  float* selfc   = (float*)alloc((size_t)NN * 4);
  int*   csr_src = (int*)  alloc((size_t)NE * 4);
  float* csr_coef= (float*)alloc((size_t)NE * 4);
  float* aggx    = (float*)alloc((size_t)NN * 32 * 4);
  bf16*  T2      = (bf16*) alloc((size_t)NN * 400 * 2);
  bf16*  T3      = (bf16*) alloc((size_t)NN * 300 * 2);
  float* gbuf    = (float*)alloc((size_t)NG * 300 * 4);
  float* a1      = (float*)alloc((size_t)NG * 200 * 4);
  float* a2      = (float*)alloc((size_t)NG * 100 * 4);
  float* logits  = (float*)alloc((size_t)NG * 6 * 4);
  // peak ~85 MB (prev round: 274 MB -> suspected d_ws overflow -> GPU fault)

  // CSR build
  k_zero_i32<<<(NN + 255) / 256, 256, 0, stream>>>(counts, NN);
  k_count<<<(NE + 255) / 256, 256, 0, stream>>>(dstA, counts, NE);
  k_dinv<<<(NN + 255) / 256, 256, 0, stream>>>(counts, dinv, selfc, NN);
  k_scan<<<1, 1024, 0, stream>>>(counts, row_ptr, fill, NN);
  k_fill<<<(NE + 255) / 256, 256, 0, stream>>>(srcA, dstA, row_ptr, fill, dinv,
                                               csr_src, csr_coef, NE);
  // layer 1: aggregate x first (linearity), then fused (19->500->400) to T2
  k_agg_x<<<(NN + 7) / 8, 256, 0, stream>>>(x, row_ptr, csr_src, csr_coef, selfc, aggx, NN);
  k_fused12<<<NN / 16, 256, 0, stream>>>(aggx, W1, b1, W2, T2);
  // layer 2 agg + layer 3 linear
  k_fused23<<<NN / 16, 256, 0, stream>>>(T2, row_ptr, csr_src, csr_coef, selfc, b2, W3, T3);
  // layer 3 agg + relu + max pool
  k_zero_f32<<<(NG * 300 + 255) / 256, 256, 0, stream>>>(gbuf, NG * 300);
  k_fused3m<<<NN / 16, 256, 0, stream>>>(T3, row_ptr, csr_src, csr_coef, selfc, b3, batch, gbuf);
  // head MLP + softmax over dim 0
  k_linear<<<(NG * 200 + 255) / 256, 256, 0, stream>>>(gbuf, Wl1, bl1, a1, NG, 200, 300, 1);
  k_linear<<<(NG * 100 + 255) / 256, 256, 0, stream>>>(a1, Wl2, bl2, a2, NG, 100, 200, 1);
  k_linear<<<(NG * 6 + 255) / 256, 256, 0, stream>>>(a2, Wl3, bl3, logits, NG, 6, 100, 0);
  k_softmax0<<<1, 256, 0, stream>>>(logits, (float*)d_out);
}

// Round 3
// 1319.513 us; speedup vs baseline: 2.2242x; 2.2242x over previous
//
#include <hip/hip_runtime.h>
#include <hip/hip_bf16.h>

#define NN 50000
#define NNP 50016   // padded to 32*1563
#define NE 800000
#define NG 256

typedef __attribute__((ext_vector_type(8))) short short8;
typedef __attribute__((ext_vector_type(8))) unsigned short ushort8;
typedef __attribute__((ext_vector_type(4))) float f32x4;

__device__ __forceinline__ float u2f(unsigned short u) {
  unsigned int t = ((unsigned int)u) << 16;
  return __builtin_bit_cast(float, t);
}
__device__ __forceinline__ unsigned short f2b(float f) {
  __hip_bfloat16 b = __float2bfloat16(f);
  return __builtin_bit_cast(unsigned short, b);
}
__device__ __forceinline__ f32x4 mfma_bf16(short8 a, short8 b, f32x4 c) {
  return __builtin_amdgcn_mfma_f32_16x16x32_bf16(a, b, c, 0, 0, 0);
}

// ---------------- CSR build ----------------
__global__ void k_zero_i32(int* __restrict__ p, int n) {
  int i = blockIdx.x * blockDim.x + threadIdx.x;
  if (i < n) p[i] = 0;
}
__global__ void k_zero_f32(float* __restrict__ p, int n) {
  int i = blockIdx.x * blockDim.x + threadIdx.x;
  if (i < n) p[i] = 0.f;
}
__global__ void k_count(const int* __restrict__ dst, int* __restrict__ counts, int E) {
  int e = blockIdx.x * blockDim.x + threadIdx.x;
  if (e < E) atomicAdd(&counts[dst[e]], 1);
}
__global__ void k_dinv(const int* __restrict__ counts, float* __restrict__ dinv,
                       float* __restrict__ selfc, int n) {
  int i = blockIdx.x * blockDim.x + threadIdx.x;
  if (i < n) {
    float d = (float)counts[i] + 1.0f;
    dinv[i]  = rsqrtf(d);
    selfc[i] = 1.0f / d;
  }
}
__global__ void k_scan(const int* __restrict__ counts, int* __restrict__ row_ptr,
                       int* __restrict__ fill, int n) {
  __shared__ int wsum[16];
  __shared__ int carry_s;
  int tid = threadIdx.x;
  if (tid == 0) carry_s = 0;
  __syncthreads();
  for (int base = 0; base < n; base += 1024) {
    int i = base + tid;
    int v = (i < n) ? counts[i] : 0;
    int incl = v;
    #pragma unroll
    for (int off = 1; off < 64; off <<= 1) {
      int t = __shfl_up(incl, off, 64);
      if ((tid & 63) >= off) incl += t;
    }
    int wid = tid >> 6;
    if ((tid & 63) == 63) wsum[wid] = incl;
    __syncthreads();
    if (tid < 16) {
      int s = wsum[tid];
      #pragma unroll
      for (int off = 1; off < 16; off <<= 1) {
        int t = __shfl_up(s, off, 16);
        if (tid >= off) s += t;
      }
      wsum[tid] = s;
    }
    __syncthreads();
    int waveoff = (wid == 0) ? 0 : wsum[wid - 1];
    int carry = carry_s;
    int excl = carry + waveoff + incl - v;
    if (i < n) { row_ptr[i] = excl; fill[i] = 0; }
    if (i == n - 1) row_ptr[n] = excl + v;
    __syncthreads();
    if (tid == 0) carry_s = carry + wsum[15];
    __syncthreads();
  }
}
__global__ void k_fill(const int* __restrict__ src, const int* __restrict__ dst,
                       const int* __restrict__ row_ptr, int* __restrict__ fill,
                       const float* __restrict__ dinv, int* __restrict__ csr_src,
                       float* __restrict__ csr_coef, int E) {
  int e = blockIdx.x * blockDim.x + threadIdx.x;
  if (e < E) {
    int s = src[e], d = dst[e];
    int pos = row_ptr[d] + atomicAdd(&fill[d], 1);
    csr_src[pos]  = s;
    csr_coef[pos] = dinv[s] * dinv[d];
  }
}

// ---------------- weight prep: bf16 transposed [N][K] with zero pad ----------------
__global__ void k_prep_w1t(const float* __restrict__ W1, unsigned short* __restrict__ W1t) {
  int idx = blockIdx.x * blockDim.x + threadIdx.x;   // 512*32
  if (idx < 512 * 32) {
    int n = idx >> 5, k = idx & 31;
    float v = (n < 500 && k < 19) ? W1[k * 500 + n] : 0.f;
    W1t[idx] = f2b(v);
  }
}
__global__ void k_prep_w2t(const float* __restrict__ W2, unsigned short* __restrict__ W2t) {
  int idx = blockIdx.x * blockDim.x + threadIdx.x;   // 416*512
  if (idx < 416 * 512) {
    int n = idx >> 9, k = idx & 511;
    float v = (n < 400 && k < 500) ? W2[k * 400 + n] : 0.f;
    W2t[idx] = f2b(v);
  }
}
__global__ void k_prep_w3t(const float* __restrict__ W3, unsigned short* __restrict__ W3t) {
  int idx = blockIdx.x * blockDim.x + threadIdx.x;   // 320*416
  if (idx < 320 * 416) {
    int n = idx / 416, k = idx - n * 416;
    float v = (n < 300 && k < 400) ? W3[k * 300 + n] : 0.f;
    W3t[idx] = f2b(v);
  }
}
__global__ void k_prep_b1(const float* __restrict__ b1, float* __restrict__ b1p) {
  int i = blockIdx.x * blockDim.x + threadIdx.x;
  if (i < 512) b1p[i] = (i < 500) ? b1[i] : 0.f;
}

// ---------------- layer-1 aggregation of x -> bf16 [NNP][32] ----------------
__global__ __launch_bounds__(256) void k_agg_x(
    const float* __restrict__ x, const int* __restrict__ row_ptr,
    const int* __restrict__ csr_src, const float* __restrict__ csr_coef,
    const float* __restrict__ selfc, unsigned short* __restrict__ aggxb, int n) {
  int tid  = threadIdx.x;
  int node = blockIdx.x * 8 + (tid >> 5);
  int lane = tid & 31;
  if (node >= NNP) return;
  float acc = 0.f;
  if (node < n && lane < 19) {
    int e0 = row_ptr[node], e1 = row_ptr[node + 1];
    for (int e = e0; e < e1; e++)
      acc += csr_coef[e] * x[(size_t)csr_src[e] * 19 + lane];
    acc += selfc[node] * x[(size_t)node * 19 + lane];
  }
  aggxb[(size_t)node * 32 + lane] = (node < n && lane < 19) ? f2b(acc) : (unsigned short)0;
}

// ---- fused layer1+2: T2 = (relu(aggx@W1+b1)) @ W2, MFMA, H1 tile in LDS ----
// block = 256 thr (4 waves), 32 rows; grid = NNP/32 = 1563
__global__ __launch_bounds__(256) void k_fused12(
    const unsigned short* __restrict__ aggxb, const unsigned short* __restrict__ W1t,
    const float* __restrict__ b1p, const unsigned short* __restrict__ W2t,
    unsigned short* __restrict__ T2) {
  __shared__ unsigned short Hs[32][520];  // 520: 16B-aligned rows, stride%128B==16B -> 2-way banks (free)
  int tid = threadIdx.x;
  int lane = tid & 63, wv = tid >> 6;
  int l15 = lane & 15, quad = lane >> 4;
  int r0 = blockIdx.x * 32;
  // phase A: Hs = relu(aggx@W1 + b1), 2x32 tiles of 16x16, K=32 (one MFMA each)
  for (int t = wv; t < 64; t += 4) {
    int rt = t & 1, ct = t >> 1;
    short8 a = *(const short8*)(aggxb + (size_t)(r0 + rt * 16 + l15) * 32 + quad * 8);
    short8 b = *(const short8*)(W1t + (size_t)(ct * 16 + l15) * 32 + quad * 8);
    f32x4 c = {0.f, 0.f, 0.f, 0.f};
    c = mfma_bf16(a, b, c);
    int col = ct * 16 + l15;
    float bias = b1p[col];
    int rbase = rt * 16 + quad * 4;
    #pragma unroll
    for (int r = 0; r < 4; r++)
      Hs[rbase + r][col] = f2b(fmaxf(c[r] + bias, 0.f));
  }
  __syncthreads();
  // phase B: T2 = Hs @ W2 (K=512 padded, N=416 padded -> 26 col-tiles)
  int rt = wv >> 1, p = wv & 1;
  f32x4 acc[13];
  #pragma unroll
  for (int j = 0; j < 13; j++) acc[j] = (f32x4){0.f, 0.f, 0.f, 0.f};
  for (int k0 = 0; k0 < 512; k0 += 32) {
    short8 a = *(const short8*)&Hs[rt * 16 + l15][k0 + quad * 8];
    #pragma unroll
    for (int j = 0; j < 13; j++) {
      int n = (p + 2 * j) * 16 + l15;
      short8 b = *(const short8*)(W2t + (size_t)n * 512 + k0 + quad * 8);
      acc[j] = mfma_bf16(a, b, acc[j]);
    }
  }
  int rr = r0 + rt * 16 + quad * 4;
  #pragma unroll
  for (int j = 0; j < 13; j++) {
    int n = (p + 2 * j) * 16 + l15;
    if (n < 400) {
      #pragma unroll
      for (int r = 0; r < 4; r++) {
        int row = rr + r;
        if (row < NN) T2[(size_t)row * 400 + n] = f2b(acc[j][r]);
      }
    }
  }
}

// ---- fused layer2 agg + layer3 linear: T3 = relu(agg(T2)+b2) @ W3 (MFMA) ----
// block 256 (4 waves), 32 rows; phase A: wave-per-node gather
__global__ __launch_bounds__(256) void k_fused23(
    const unsigned short* __restrict__ T2, const int* __restrict__ row_ptr,
    const int* __restrict__ csr_src, const float* __restrict__ csr_coef,
    const float* __restrict__ selfc, const float* __restrict__ b2,
    const unsigned short* __restrict__ W3t, unsigned short* __restrict__ T3) {
  __shared__ unsigned short Hs[32][424];  // 424: 16B-aligned, 2-way banks
  int tid = threadIdx.x;
  int lane = tid & 63, wv = tid >> 6;
  int l15 = lane & 15, quad = lane >> 4;
  int r0 = blockIdx.x * 32;
  bool act = lane < 50;
  int cb = lane * 8;
  for (int i = 0; i < 8; i++) {
    int nl = wv + 4 * i;
    int node = r0 + nl;
    if (node < NN && act) {
      float acc[8];
      #pragma unroll
      for (int j = 0; j < 8; j++) acc[j] = 0.f;
      int e0 = row_ptr[node], e1 = row_ptr[node + 1];
      if (e0 < e1) {
        int s = csr_src[e0];
        float cf = csr_coef[e0];
        ushort8 v = *(const ushort8*)(T2 + (size_t)s * 400 + cb);
        for (int e = e0; e < e1; e++) {
          ushort8 vn; int sn; float cfn;
          if (e + 1 < e1) {
            sn = csr_src[e + 1]; cfn = csr_coef[e + 1];
            vn = *(const ushort8*)(T2 + (size_t)sn * 400 + cb);
          }
          #pragma unroll
          for (int j = 0; j < 8; j++) acc[j] += cf * u2f(v[j]);
          v = vn; cf = cfn;
        }
      }
      ushort8 sv = *(const ushort8*)(T2 + (size_t)node * 400 + cb);
      float sc = selfc[node];
      ushort8 hv;
      #pragma unroll
      for (int j = 0; j < 8; j++) {
        float val = fmaxf(acc[j] + sc * u2f(sv[j]) + b2[cb + j], 0.f);
        hv[j] = f2b(val);
      }
      *(ushort8*)&Hs[nl][cb] = hv;
    } else if (lane < 52) {
      // zero pad cols 400..415 (and whole row for pad nodes)
      *(ushort8*)&Hs[nl][cb] = (ushort8)0;
    }
  }
  __syncthreads();
  // phase B: T3 = Hs @ W3t, K=416 pad, N=320 pad -> 20 col-tiles
  int rt = wv >> 1, p = wv & 1;
  f32x4 acc[10];
  #pragma unroll
  for (int j = 0; j < 10; j++) acc[j] = (f32x4){0.f, 0.f, 0.f, 0.f};
  for (int k0 = 0; k0 < 416; k0 += 32) {
    short8 a = *(const short8*)&Hs[rt * 16 + l15][k0 + quad * 8];
    #pragma unroll
    for (int j = 0; j < 10; j++) {
      int n = (p + 2 * j) * 16 + l15;
      short8 b = *(const short8*)(W3t + (size_t)n * 416 + k0 + quad * 8);
      acc[j] = mfma_bf16(a, b, acc[j]);
    }
  }
  int rr = r0 + rt * 16 + quad * 4;
  #pragma unroll
  for (int j = 0; j < 10; j++) {
    int n = (p + 2 * j) * 16 + l15;
    if (n < 300) {
      #pragma unroll
      for (int r = 0; r < 4; r++) {
        int row = rr + r;
        if (row < NN) T3[(size_t)row * 304 + n] = f2b(acc[j][r]);
      }
    }
  }
}

// ---- fused layer3 agg + bias + relu + per-graph atomic max pool ----
// wave per node; T3 row stride 304 (pad cols masked at write)
__global__ __launch_bounds__(256) void k_fused3m(
    const unsigned short* __restrict__ T3, const int* __restrict__ row_ptr,
    const int* __restrict__ csr_src, const float* __restrict__ csr_coef,
    const float* __restrict__ selfc, const float* __restrict__ b3,
    const int* __restrict__ batch, float* __restrict__ gbuf) {
  int tid = threadIdx.x;
  int lane = tid & 63, wv = tid >> 6;
  int node = blockIdx.x * 4 + wv;
  if (node >= NN) return;
  bool act = lane < 38;
  int cb = lane * 8;
  float acc[8];
  #pragma unroll
  for (int j = 0; j < 8; j++) acc[j] = 0.f;
  if (act) {
    int e0 = row_ptr[node], e1 = row_ptr[node + 1];
    if (e0 < e1) {
      int s = csr_src[e0];
      float cf = csr_coef[e0];
      ushort8 v = *(const ushort8*)(T3 + (size_t)s * 304 + cb);
      for (int e = e0; e < e1; e++) {
        ushort8 vn; int sn; float cfn;
        if (e + 1 < e1) {
          sn = csr_src[e + 1]; cfn = csr_coef[e + 1];
          vn = *(const ushort8*)(T3 + (size_t)sn * 304 + cb);
        }
        #pragma unroll
        for (int j = 0; j < 8; j++) acc[j] += cf * u2f(v[j]);
        v = vn; cf = cfn;
      }
    }
    ushort8 sv = *(const ushort8*)(T3 + (size_t)node * 304 + cb);
    float sc = selfc[node];
    int gi = batch[node];
    #pragma unroll
    for (int j = 0; j < 8; j++) {
      int c = cb + j;
      if (c < 300) {
        float v = fmaxf(acc[j] + sc * u2f(sv[j]) + b3[c], 0.f);
        atomicMax((unsigned int*)&gbuf[(size_t)gi * 300 + c], __float_as_uint(v));
      }
    }
  }
}

// ---------------- small dense head ----------------
__global__ void k_linear(const float* __restrict__ A, const float* __restrict__ W,
                         const float* __restrict__ b, float* __restrict__ C,
                         int M, int N, int K, int relu) {
  int idx = blockIdx.x * blockDim.x + threadIdx.x;
  if (idx >= M * N) return;
  int m = idx / N, n = idx - m * N;
  float acc = b[n];
  for (int k = 0; k < K; k++) acc += A[m * K + k] * W[k * N + n];
  if (relu) acc = fmaxf(acc, 0.f);
  C[idx] = acc;
}

__global__ void k_softmax0(const float* __restrict__ logits, float* __restrict__ out) {
  __shared__ float cmax[6], csum[6];
  int g = threadIdx.x;
  if (g < 6) {
    float m = -1e30f;
    for (int i = 0; i < NG; i++) m = fmaxf(m, logits[i * 6 + g]);
    float s = 0.f;
    for (int i = 0; i < NG; i++) s += expf(logits[i * 6 + g] - m);
    cmax[g] = m; csum[g] = s;
  }
  __syncthreads();
  for (int c = 0; c < 6; c++)
    out[g * 6 + c] = expf(logits[g * 6 + c] - cmax[c]) / csum[c];
}

extern "C" void kernel_launch(void* const* d_in, const int* in_sizes, int n_in,
                              void* d_out, int out_size, void* d_ws, size_t ws_size,
                              hipStream_t stream) {
  const float* x    = (const float*)d_in[0];
  const int*   eidx = (const int*)d_in[1];
  const int*   batch= (const int*)d_in[2];
  const float* W1 = (const float*)d_in[3];  const float* b1 = (const float*)d_in[4];
  const float* W2 = (const float*)d_in[5];  const float* b2 = (const float*)d_in[6];
  const float* W3 = (const float*)d_in[7];  const float* b3 = (const float*)d_in[8];
  const float* Wl1= (const float*)d_in[9];  const float* bl1= (const float*)d_in[10];
  const float* Wl2= (const float*)d_in[11]; const float* bl2= (const float*)d_in[12];
  const float* Wl3= (const float*)d_in[13]; const float* bl3= (const float*)d_in[14];
  const int* srcA = eidx;
  const int* dstA = eidx + NE;

  char* ws = (char*)d_ws;
  size_t off = 0;
  auto alloc = [&](size_t bytes) -> char* {
    char* p = ws + off;
    off = (off + bytes + 255) & ~(size_t)255;
    return p;
  };
  int*   counts  = (int*)  alloc((size_t)NN * 4);
  int*   row_ptr = (int*)  alloc((size_t)(NN + 1) * 4);
  int*   fill    = (int*)  alloc((size_t)NN * 4);
  float* dinv    = (float*)alloc((size_t)NN * 4);
  float* selfc   = (float*)alloc((size_t)NN * 4);
  int*   csr_src = (int*)  alloc((size_t)NE * 4);
  float* csr_coef= (float*)alloc((size_t)NE * 4);
  unsigned short* aggxb = (unsigned short*)alloc((size_t)NNP * 32 * 2);
  unsigned short* W1t   = (unsigned short*)alloc((size_t)512 * 32 * 2);
  unsigned short* W2t   = (unsigned short*)alloc((size_t)416 * 512 * 2);
  unsigned short* W3t   = (unsigned short*)alloc((size_t)320 * 416 * 2);
  float* b1p     = (float*)alloc(512 * 4);
  unsigned short* T2 = (unsigned short*)alloc((size_t)NNP * 400 * 2);
  unsigned short* T3 = (unsigned short*)alloc((size_t)NNP * 304 * 2);
  float* gbuf    = (float*)alloc((size_t)NG * 300 * 4);
  float* a1      = (float*)alloc((size_t)NG * 200 * 4);
  float* a2      = (float*)alloc((size_t)NG * 100 * 4);
  float* logits  = (float*)alloc((size_t)NG * 6 * 4);
  // peak ~82 MB

  // CSR build
  k_zero_i32<<<(NN + 255) / 256, 256, 0, stream>>>(counts, NN);
  k_count<<<(NE + 255) / 256, 256, 0, stream>>>(dstA, counts, NE);
  k_dinv<<<(NN + 255) / 256, 256, 0, stream>>>(counts, dinv, selfc, NN);
  k_scan<<<1, 1024, 0, stream>>>(counts, row_ptr, fill, NN);
  k_fill<<<(NE + 255) / 256, 256, 0, stream>>>(srcA, dstA, row_ptr, fill, dinv,
                                               csr_src, csr_coef, NE);
  // weight prep (bf16, transposed, padded)
  k_prep_w1t<<<(512 * 32 + 255) / 256, 256, 0, stream>>>(W1, W1t);
  k_prep_w2t<<<(416 * 512 + 255) / 256, 256, 0, stream>>>(W2, W2t);
  k_prep_w3t<<<(320 * 416 + 255) / 256, 256, 0, stream>>>(W3, W3t);
  k_prep_b1<<<2, 256, 0, stream>>>(b1, b1p);
  // layer 1: aggregate x first (linearity), then fused MFMA (19->500->400) to T2
  k_agg_x<<<(NNP + 7) / 8, 256, 0, stream>>>(x, row_ptr, csr_src, csr_coef, selfc, aggxb, NN);
  k_fused12<<<NNP / 32, 256, 0, stream>>>(aggxb, W1t, b1p, W2t, T2);
  // layer 2 agg + layer 3 linear (MFMA)
  k_fused23<<<NNP / 32, 256, 0, stream>>>(T2, row_ptr, csr_src, csr_coef, selfc, b2, W3t, T3);
  // layer 3 agg + relu + max pool
  k_zero_f32<<<(NG * 300 + 255) / 256, 256, 0, stream>>>(gbuf, NG * 300);
  k_fused3m<<<(NN + 3) / 4, 256, 0, stream>>>(T3, row_ptr, csr_src, csr_coef, selfc, b3, batch, gbuf);
  // head MLP + softmax over dim 0
  k_linear<<<(NG * 200 + 255) / 256, 256, 0, stream>>>(gbuf, Wl1, bl1, a1, NG, 200, 300, 1);
  k_linear<<<(NG * 100 + 255) / 256, 256, 0, stream>>>(a1, Wl2, bl2, a2, NG, 100, 200, 1);
  k_linear<<<(NG * 6 + 255) / 256, 256, 0, stream>>>(a2, Wl3, bl3, logits, NG, 6, 100, 0);
  k_softmax0<<<1, 256, 0, stream>>>(logits, (float*)d_out);
}

// Round 4
// 1050.042 us; speedup vs baseline: 2.7950x; 1.2566x over previous
//
#include <hip/hip_runtime.h>
#include <hip/hip_bf16.h>

#define NN 50000
#define NNP 50016   // padded to 32*1563
#define NE 800000
#define NG 256

typedef __attribute__((ext_vector_type(8))) short short8;
typedef __attribute__((ext_vector_type(8))) unsigned short ushort8;
typedef __attribute__((ext_vector_type(4))) float f32x4;

__device__ __forceinline__ float u2f(unsigned short u) {
  unsigned int t = ((unsigned int)u) << 16;
  return __builtin_bit_cast(float, t);
}
__device__ __forceinline__ unsigned short f2b(float f) {
  __hip_bfloat16 b = __float2bfloat16(f);
  return __builtin_bit_cast(unsigned short, b);
}
__device__ __forceinline__ f32x4 mfma_bf16(short8 a, short8 b, f32x4 c) {
  return __builtin_amdgcn_mfma_f32_16x16x32_bf16(a, b, c, 0, 0, 0);
}

// ---------------- CSR build ----------------
__global__ void k_zero_i32(int* __restrict__ p, int n) {
  int i = blockIdx.x * blockDim.x + threadIdx.x;
  if (i < n) p[i] = 0;
}
__global__ void k_zero_f32(float* __restrict__ p, int n) {
  int i = blockIdx.x * blockDim.x + threadIdx.x;
  if (i < n) p[i] = 0.f;
}
__global__ void k_count(const int* __restrict__ dst, int* __restrict__ counts, int E) {
  int e = blockIdx.x * blockDim.x + threadIdx.x;
  if (e < E) atomicAdd(&counts[dst[e]], 1);
}
__global__ void k_dinv(const int* __restrict__ counts, float* __restrict__ dinv,
                       float* __restrict__ selfc, int n) {
  int i = blockIdx.x * blockDim.x + threadIdx.x;
  if (i < n) {
    float d = (float)counts[i] + 1.0f;
    dinv[i]  = rsqrtf(d);
    selfc[i] = 1.0f / d;
  }
}
__global__ void k_scan(const int* __restrict__ counts, int* __restrict__ row_ptr,
                       int* __restrict__ fill, int n) {
  __shared__ int wsum[16];
  __shared__ int carry_s;
  int tid = threadIdx.x;
  if (tid == 0) carry_s = 0;
  __syncthreads();
  for (int base = 0; base < n; base += 1024) {
    int i = base + tid;
    int v = (i < n) ? counts[i] : 0;
    int incl = v;
    #pragma unroll
    for (int off = 1; off < 64; off <<= 1) {
      int t = __shfl_up(incl, off, 64);
      if ((tid & 63) >= off) incl += t;
    }
    int wid = tid >> 6;
    if ((tid & 63) == 63) wsum[wid] = incl;
    __syncthreads();
    if (tid < 16) {
      int s = wsum[tid];
      #pragma unroll
      for (int off = 1; off < 16; off <<= 1) {
        int t = __shfl_up(s, off, 16);
        if (tid >= off) s += t;
      }
      wsum[tid] = s;
    }
    __syncthreads();
    int waveoff = (wid == 0) ? 0 : wsum[wid - 1];
    int carry = carry_s;
    int excl = carry + waveoff + incl - v;
    if (i < n) { row_ptr[i] = excl; fill[i] = 0; }
    if (i == n - 1) row_ptr[n] = excl + v;
    __syncthreads();
    if (tid == 0) carry_s = carry + wsum[15];
    __syncthreads();
  }
}
__global__ void k_fill(const int* __restrict__ src, const int* __restrict__ dst,
                       const int* __restrict__ row_ptr, int* __restrict__ fill,
                       const float* __restrict__ dinv, int* __restrict__ csr_src,
                       float* __restrict__ csr_coef, int E) {
  int e = blockIdx.x * blockDim.x + threadIdx.x;
  if (e < E) {
    int s = src[e], d = dst[e];
    int pos = row_ptr[d] + atomicAdd(&fill[d], 1);
    csr_src[pos]  = s;
    csr_coef[pos] = dinv[s] * dinv[d];
  }
}

// ---------------- weight prep: bf16 transposed [N][K] with zero pad ----------------
__global__ void k_prep_w1t(const float* __restrict__ W1, unsigned short* __restrict__ W1t) {
  int idx = blockIdx.x * blockDim.x + threadIdx.x;   // 512*32
  if (idx < 512 * 32) {
    int n = idx >> 5, k = idx & 31;
    float v = (n < 500 && k < 19) ? W1[k * 500 + n] : 0.f;
    W1t[idx] = f2b(v);
  }
}
__global__ void k_prep_w2t(const float* __restrict__ W2, unsigned short* __restrict__ W2t) {
  int idx = blockIdx.x * blockDim.x + threadIdx.x;   // 416*512
  if (idx < 416 * 512) {
    int n = idx >> 9, k = idx & 511;
    float v = (n < 400 && k < 500) ? W2[k * 400 + n] : 0.f;
    W2t[idx] = f2b(v);
  }
}
__global__ void k_prep_w3t(const float* __restrict__ W3, unsigned short* __restrict__ W3t) {
  int idx = blockIdx.x * blockDim.x + threadIdx.x;   // 320*416
  if (idx < 320 * 416) {
    int n = idx / 416, k = idx - n * 416;
    float v = (n < 300 && k < 400) ? W3[k * 300 + n] : 0.f;
    W3t[idx] = f2b(v);
  }
}
__global__ void k_prep_b1(const float* __restrict__ b1, float* __restrict__ b1p) {
  int i = blockIdx.x * blockDim.x + threadIdx.x;
  if (i < 512) b1p[i] = (i < 500) ? b1[i] : 0.f;
}

// ---------------- layer-1 aggregation of x -> bf16 [NNP][32] ----------------
__global__ __launch_bounds__(256) void k_agg_x(
    const float* __restrict__ x, const int* __restrict__ row_ptr,
    const int* __restrict__ csr_src, const float* __restrict__ csr_coef,
    const float* __restrict__ selfc, unsigned short* __restrict__ aggxb, int n) {
  int tid  = threadIdx.x;
  int node = blockIdx.x * 8 + (tid >> 5);
  int lane = tid & 31;
  if (node >= NNP) return;
  float acc = 0.f;
  if (node < n && lane < 19) {
    int e0 = row_ptr[node], e1 = row_ptr[node + 1];
    for (int e = e0; e < e1; e++)
      acc += csr_coef[e] * x[(size_t)csr_src[e] * 19 + lane];
    acc += selfc[node] * x[(size_t)node * 19 + lane];
  }
  aggxb[(size_t)node * 32 + lane] = (node < n && lane < 19) ? f2b(acc) : (unsigned short)0;
}

// ---- fused layer1+2: T2 = (relu(aggx@W1+b1)) @ W2, MFMA, H1 tile in LDS ----
__global__ __launch_bounds__(256) void k_fused12(
    const unsigned short* __restrict__ aggxb, const unsigned short* __restrict__ W1t,
    const float* __restrict__ b1p, const unsigned short* __restrict__ W2t,
    unsigned short* __restrict__ T2) {
  __shared__ unsigned short Hs[32][520];
  int tid = threadIdx.x;
  int lane = tid & 63, wv = tid >> 6;
  int l15 = lane & 15, quad = lane >> 4;
  int r0 = blockIdx.x * 32;
  for (int t = wv; t < 64; t += 4) {
    int rt = t & 1, ct = t >> 1;
    short8 a = *(const short8*)(aggxb + (size_t)(r0 + rt * 16 + l15) * 32 + quad * 8);
    short8 b = *(const short8*)(W1t + (size_t)(ct * 16 + l15) * 32 + quad * 8);
    f32x4 c = {0.f, 0.f, 0.f, 0.f};
    c = mfma_bf16(a, b, c);
    int col = ct * 16 + l15;
    float bias = b1p[col];
    int rbase = rt * 16 + quad * 4;
    #pragma unroll
    for (int r = 0; r < 4; r++)
      Hs[rbase + r][col] = f2b(fmaxf(c[r] + bias, 0.f));
  }
  __syncthreads();
  int rt = wv >> 1, p = wv & 1;
  f32x4 acc[13];
  #pragma unroll
  for (int j = 0; j < 13; j++) acc[j] = (f32x4){0.f, 0.f, 0.f, 0.f};
  for (int k0 = 0; k0 < 512; k0 += 32) {
    short8 a = *(const short8*)&Hs[rt * 16 + l15][k0 + quad * 8];
    #pragma unroll
    for (int j = 0; j < 13; j++) {
      int n = (p + 2 * j) * 16 + l15;
      short8 b = *(const short8*)(W2t + (size_t)n * 512 + k0 + quad * 8);
      acc[j] = mfma_bf16(a, b, acc[j]);
    }
  }
  int rr = r0 + rt * 16 + quad * 4;
  #pragma unroll
  for (int j = 0; j < 13; j++) {
    int n = (p + 2 * j) * 16 + l15;
    if (n < 400) {
      #pragma unroll
      for (int r = 0; r < 4; r++) {
        int row = rr + r;
        if (row < NN) T2[(size_t)row * 400 + n] = f2b(acc[j][r]);
      }
    }
  }
}

// ---- fused layer2 agg + layer3 linear: T3 = relu(agg(T2)+b2) @ W3 (MFMA) ----
__global__ __launch_bounds__(256) void k_fused23(
    const unsigned short* __restrict__ T2, const int* __restrict__ row_ptr,
    const int* __restrict__ csr_src, const float* __restrict__ csr_coef,
    const float* __restrict__ selfc, const float* __restrict__ b2,
    const unsigned short* __restrict__ W3t, unsigned short* __restrict__ T3) {
  __shared__ unsigned short Hs[32][424];
  int tid = threadIdx.x;
  int lane = tid & 63, wv = tid >> 6;
  int l15 = lane & 15, quad = lane >> 4;
  int r0 = blockIdx.x * 32;
  bool act = lane < 50;
  int cb = lane * 8;
  for (int i = 0; i < 8; i++) {
    int nl = wv + 4 * i;
    int node = r0 + nl;
    if (node < NN && act) {
      float acc[8];
      #pragma unroll
      for (int j = 0; j < 8; j++) acc[j] = 0.f;
      int e0 = row_ptr[node], e1 = row_ptr[node + 1];
      if (e0 < e1) {
        int s = csr_src[e0];
        float cf = csr_coef[e0];
        ushort8 v = *(const ushort8*)(T2 + (size_t)s * 400 + cb);
        for (int e = e0; e < e1; e++) {
          ushort8 vn; int sn; float cfn;
          if (e + 1 < e1) {
            sn = csr_src[e + 1]; cfn = csr_coef[e + 1];
            vn = *(const ushort8*)(T2 + (size_t)sn * 400 + cb);
          }
          #pragma unroll
          for (int j = 0; j < 8; j++) acc[j] += cf * u2f(v[j]);
          v = vn; cf = cfn;
        }
      }
      ushort8 sv = *(const ushort8*)(T2 + (size_t)node * 400 + cb);
      float sc = selfc[node];
      ushort8 hv;
      #pragma unroll
      for (int j = 0; j < 8; j++) {
        float val = fmaxf(acc[j] + sc * u2f(sv[j]) + b2[cb + j], 0.f);
        hv[j] = f2b(val);
      }
      *(ushort8*)&Hs[nl][cb] = hv;
    } else if (lane < 52) {
      *(ushort8*)&Hs[nl][cb] = (ushort8)0;
    }
  }
  __syncthreads();
  int rt = wv >> 1, p = wv & 1;
  f32x4 acc[10];
  #pragma unroll
  for (int j = 0; j < 10; j++) acc[j] = (f32x4){0.f, 0.f, 0.f, 0.f};
  for (int k0 = 0; k0 < 416; k0 += 32) {
    short8 a = *(const short8*)&Hs[rt * 16 + l15][k0 + quad * 8];
    #pragma unroll
    for (int j = 0; j < 10; j++) {
      int n = (p + 2 * j) * 16 + l15;
      short8 b = *(const short8*)(W3t + (size_t)n * 416 + k0 + quad * 8);
      acc[j] = mfma_bf16(a, b, acc[j]);
    }
  }
  int rr = r0 + rt * 16 + quad * 4;
  #pragma unroll
  for (int j = 0; j < 10; j++) {
    int n = (p + 2 * j) * 16 + l15;
    if (n < 300) {
      #pragma unroll
      for (int r = 0; r < 4; r++) {
        int row = rr + r;
        if (row < NN) T3[(size_t)row * 304 + n] = f2b(acc[j][r]);
      }
    }
  }
}

// ---- fused layer3 agg + bias + relu + per-graph max pool ----
// batch is SORTED: 32 consecutive nodes span ~1-2 graphs. Accumulate max in a
// 4-slot LDS table (float-as-uint, values >= 0), flush <=4x300 atomics/block.
// R3 evidence: per-element atomicMax produced WRITE_SIZE=480MB (15M x 32B).
__global__ __launch_bounds__(256) void k_fused3m(
    const unsigned short* __restrict__ T3, const int* __restrict__ row_ptr,
    const int* __restrict__ csr_src, const float* __restrict__ csr_coef,
    const float* __restrict__ selfc, const float* __restrict__ b3,
    const int* __restrict__ batch, float* __restrict__ gbuf) {
  __shared__ unsigned int lmax[4][304];
  int tid = threadIdx.x;
  int lane = tid & 63, wv = tid >> 6;
  int r0 = blockIdx.x * 32;
  int g0 = batch[r0];
  for (int i = tid; i < 4 * 304; i += 256) ((unsigned int*)lmax)[i] = 0u;
  __syncthreads();
  bool act = lane < 38;
  int cb = lane * 8;
  for (int i = 0; i < 8; i++) {
    int node = r0 + wv * 8 + i;
    if (node >= NN) break;
    float acc[8];
    #pragma unroll
    for (int j = 0; j < 8; j++) acc[j] = 0.f;
    if (act) {
      int e0 = row_ptr[node], e1 = row_ptr[node + 1];
      if (e0 < e1) {
        int s = csr_src[e0];
        float cf = csr_coef[e0];
        ushort8 v = *(const ushort8*)(T3 + (size_t)s * 304 + cb);
        for (int e = e0; e < e1; e++) {
          ushort8 vn; int sn; float cfn;
          if (e + 1 < e1) {
            sn = csr_src[e + 1]; cfn = csr_coef[e + 1];
            vn = *(const ushort8*)(T3 + (size_t)sn * 304 + cb);
          }
          #pragma unroll
          for (int j = 0; j < 8; j++) acc[j] += cf * u2f(v[j]);
          v = vn; cf = cfn;
        }
      }
      ushort8 sv = *(const ushort8*)(T3 + (size_t)node * 304 + cb);
      float sc = selfc[node];
      int gi = batch[node];
      int slot = gi - g0;
      #pragma unroll
      for (int j = 0; j < 8; j++) {
        int c = cb + j;
        if (c < 300) {
          float v = fmaxf(acc[j] + sc * u2f(sv[j]) + b3[c], 0.f);
          unsigned int uv = __float_as_uint(v);
          if (slot < 4) atomicMax(&lmax[slot][c], uv);
          else atomicMax((unsigned int*)&gbuf[(size_t)gi * 300 + c], uv);  // pathological fallback
        }
      }
    }
  }
  __syncthreads();
  for (int i = tid; i < 4 * 304; i += 256) {
    int s = i >> 8 | 0;  // placeholder avoided below
    ;
  }
  // flush: slot-major so columns are coalesced
  for (int i = tid; i < 4 * 304; i += 256) {
    int s = i / 304, c = i - s * 304;
    unsigned int uv = lmax[s][c];
    int g = g0 + s;
    if (c < 300 && uv != 0u && g < NG)
      atomicMax((unsigned int*)&gbuf[(size_t)g * 300 + c], uv);
  }
}

// ---------------- small dense head ----------------
__global__ void k_linear(const float* __restrict__ A, const float* __restrict__ W,
                         const float* __restrict__ b, float* __restrict__ C,
                         int M, int N, int K, int relu) {
  int idx = blockIdx.x * blockDim.x + threadIdx.x;
  if (idx >= M * N) return;
  int m = idx / N, n = idx - m * N;
  float acc = b[n];
  for (int k = 0; k < K; k++) acc += A[m * K + k] * W[k * N + n];
  if (relu) acc = fmaxf(acc, 0.f);
  C[idx] = acc;
}

__global__ void k_softmax0(const float* __restrict__ logits, float* __restrict__ out) {
  __shared__ float cmax[6], csum[6];
  int g = threadIdx.x;
  if (g < 6) {
    float m = -1e30f;
    for (int i = 0; i < NG; i++) m = fmaxf(m, logits[i * 6 + g]);
    float s = 0.f;
    for (int i = 0; i < NG; i++) s += expf(logits[i * 6 + g] - m);
    cmax[g] = m; csum[g] = s;
  }
  __syncthreads();
  for (int c = 0; c < 6; c++)
    out[g * 6 + c] = expf(logits[g * 6 + c] - cmax[c]) / csum[c];
}

extern "C" void kernel_launch(void* const* d_in, const int* in_sizes, int n_in,
                              void* d_out, int out_size, void* d_ws, size_t ws_size,
                              hipStream_t stream) {
  const float* x    = (const float*)d_in[0];
  const int*   eidx = (const int*)d_in[1];
  const int*   batch= (const int*)d_in[2];
  const float* W1 = (const float*)d_in[3];  const float* b1 = (const float*)d_in[4];
  const float* W2 = (const float*)d_in[5];  const float* b2 = (const float*)d_in[6];
  const float* W3 = (const float*)d_in[7];  const float* b3 = (const float*)d_in[8];
  const float* Wl1= (const float*)d_in[9];  const float* bl1= (const float*)d_in[10];
  const float* Wl2= (const float*)d_in[11]; const float* bl2= (const float*)d_in[12];
  const float* Wl3= (const float*)d_in[13]; const float* bl3= (const float*)d_in[14];
  const int* srcA = eidx;
  const int* dstA = eidx + NE;

  char* ws = (char*)d_ws;
  size_t off = 0;
  auto alloc = [&](size_t bytes) -> char* {
    char* p = ws + off;
    off = (off + bytes + 255) & ~(size_t)255;
    return p;
  };
  int*   counts  = (int*)  alloc((size_t)NN * 4);
  int*   row_ptr = (int*)  alloc((size_t)(NN + 1) * 4);
  int*   fill    = (int*)  alloc((size_t)NN * 4);
  float* dinv    = (float*)alloc((size_t)NN * 4);
  float* selfc   = (float*)alloc((size_t)NN * 4);
  int*   csr_src = (int*)  alloc((size_t)NE * 4);
  float* csr_coef= (float*)alloc((size_t)NE * 4);
  unsigned short* aggxb = (unsigned short*)alloc((size_t)NNP * 32 * 2);
  unsigned short* W1t   = (unsigned short*)alloc((size_t)512 * 32 * 2);
  unsigned short* W2t   = (unsigned short*)alloc((size_t)416 * 512 * 2);
  unsigned short* W3t   = (unsigned short*)alloc((size_t)320 * 416 * 2);
  float* b1p     = (float*)alloc(512 * 4);
  unsigned short* T2 = (unsigned short*)alloc((size_t)NNP * 400 * 2);
  unsigned short* T3 = (unsigned short*)alloc((size_t)NNP * 304 * 2);
  float* gbuf    = (float*)alloc((size_t)NG * 300 * 4);
  float* a1      = (float*)alloc((size_t)NG * 200 * 4);
  float* a2      = (float*)alloc((size_t)NG * 100 * 4);
  float* logits  = (float*)alloc((size_t)NG * 6 * 4);

  // CSR build
  k_zero_i32<<<(NN + 255) / 256, 256, 0, stream>>>(counts, NN);
  k_count<<<(NE + 255) / 256, 256, 0, stream>>>(dstA, counts, NE);
  k_dinv<<<(NN + 255) / 256, 256, 0, stream>>>(counts, dinv, selfc, NN);
  k_scan<<<1, 1024, 0, stream>>>(counts, row_ptr, fill, NN);
  k_fill<<<(NE + 255) / 256, 256, 0, stream>>>(srcA, dstA, row_ptr, fill, dinv,
                                               csr_src, csr_coef, NE);
  // weight prep
  k_prep_w1t<<<(512 * 32 + 255) / 256, 256, 0, stream>>>(W1, W1t);
  k_prep_w2t<<<(416 * 512 + 255) / 256, 256, 0, stream>>>(W2, W2t);
  k_prep_w3t<<<(320 * 416 + 255) / 256, 256, 0, stream>>>(W3, W3t);
  k_prep_b1<<<2, 256, 0, stream>>>(b1, b1p);
  // layers
  k_agg_x<<<(NNP + 7) / 8, 256, 0, stream>>>(x, row_ptr, csr_src, csr_coef, selfc, aggxb, NN);
  k_fused12<<<NNP / 32, 256, 0, stream>>>(aggxb, W1t, b1p, W2t, T2);
  k_fused23<<<NNP / 32, 256, 0, stream>>>(T2, row_ptr, csr_src, csr_coef, selfc, b2, W3t, T3);
  k_zero_f32<<<(NG * 300 + 255) / 256, 256, 0, stream>>>(gbuf, NG * 300);
  k_fused3m<<<NNP / 32, 256, 0, stream>>>(T3, row_ptr, csr_src, csr_coef, selfc, b3, batch, gbuf);
  // head
  k_linear<<<(NG * 200 + 255) / 256, 256, 0, stream>>>(gbuf, Wl1, bl1, a1, NG, 200, 300, 1);
  k_linear<<<(NG * 100 + 255) / 256, 256, 0, stream>>>(a1, Wl2, bl2, a2, NG, 100, 200, 1);
  k_linear<<<(NG * 6 + 255) / 256, 256, 0, stream>>>(a2, Wl3, bl3, logits, NG, 6, 100, 0);
  k_softmax0<<<1, 256, 0, stream>>>(logits, (float*)d_out);
}

// Round 6
// 952.041 us; speedup vs baseline: 3.0827x; 1.1029x over previous
//
#include <hip/hip_runtime.h>
#include <hip/hip_bf16.h>

#define NN 50000
#define NNP 50016   // padded to 32*1563
#define NE 800000
#define NG 256

typedef __attribute__((ext_vector_type(8))) short short8;
typedef __attribute__((ext_vector_type(8))) unsigned short ushort8;
typedef __attribute__((ext_vector_type(4))) float f32x4;

__device__ __forceinline__ float u2f(unsigned short u) {
  unsigned int t = ((unsigned int)u) << 16;
  return __builtin_bit_cast(float, t);
}
__device__ __forceinline__ unsigned short f2b(float f) {
  __hip_bfloat16 b = __float2bfloat16(f);
  return __builtin_bit_cast(unsigned short, b);
}
__device__ __forceinline__ f32x4 mfma_bf16(short8 a, short8 b, f32x4 c) {
  return __builtin_amdgcn_mfma_f32_16x16x32_bf16(a, b, c, 0, 0, 0);
}
__device__ __forceinline__ void fma8(float* acc, float c, const ushort8& v) {
  #pragma unroll
  for (int j = 0; j < 8; j++) acc[j] += c * u2f(v[j]);
}

// ---------------- CSR build ----------------
__global__ void k_zero_i32(int* __restrict__ p, int n) {
  int i = blockIdx.x * blockDim.x + threadIdx.x;
  if (i < n) p[i] = 0;
}
__global__ void k_zero_f32(float* __restrict__ p, int n) {
  int i = blockIdx.x * blockDim.x + threadIdx.x;
  if (i < n) p[i] = 0.f;
}
__global__ void k_count(const int* __restrict__ dst, int* __restrict__ counts, int E) {
  int e = blockIdx.x * blockDim.x + threadIdx.x;
  if (e < E) atomicAdd(&counts[dst[e]], 1);
}
__global__ void k_dinv(const int* __restrict__ counts, float* __restrict__ dinv,
                       float* __restrict__ selfc, int n) {
  int i = blockIdx.x * blockDim.x + threadIdx.x;
  if (i < n) {
    float d = (float)counts[i] + 1.0f;
    dinv[i]  = rsqrtf(d);
    selfc[i] = 1.0f / d;
  }
}
__global__ void k_scan(const int* __restrict__ counts, int* __restrict__ row_ptr,
                       int* __restrict__ fill, int n) {
  __shared__ int wsum[16];
  __shared__ int carry_s;
  int tid = threadIdx.x;
  if (tid == 0) carry_s = 0;
  __syncthreads();
  for (int base = 0; base < n; base += 1024) {
    int i = base + tid;
    int v = (i < n) ? counts[i] : 0;
    int incl = v;
    #pragma unroll
    for (int off = 1; off < 64; off <<= 1) {
      int t = __shfl_up(incl, off, 64);
      if ((tid & 63) >= off) incl += t;
    }
    int wid = tid >> 6;
    if ((tid & 63) == 63) wsum[wid] = incl;
    __syncthreads();
    if (tid < 16) {
      int s = wsum[tid];
      #pragma unroll
      for (int off = 1; off < 16; off <<= 1) {
        int t = __shfl_up(s, off, 16);
        if (tid >= off) s += t;
      }
      wsum[tid] = s;
    }
    __syncthreads();
    int waveoff = (wid == 0) ? 0 : wsum[wid - 1];
    int carry = carry_s;
    int excl = carry + waveoff + incl - v;
    if (i < n) { row_ptr[i] = excl; fill[i] = 0; }
    if (i == n - 1) row_ptr[n] = excl + v;
    __syncthreads();
    if (tid == 0) carry_s = carry + wsum[15];
    __syncthreads();
  }
}
__global__ void k_fill(const int* __restrict__ src, const int* __restrict__ dst,
                       const int* __restrict__ row_ptr, int* __restrict__ fill,
                       const float* __restrict__ dinv, int* __restrict__ csr_src,
                       float* __restrict__ csr_coef, int E) {
  int e = blockIdx.x * blockDim.x + threadIdx.x;
  if (e < E) {
    int s = src[e], d = dst[e];
    int pos = row_ptr[d] + atomicAdd(&fill[d], 1);
    csr_src[pos]  = s;
    csr_coef[pos] = dinv[s] * dinv[d];
  }
}

// ---------------- weight prep: bf16 transposed [N][K] with zero pad ----------------
__global__ void k_prep_w1t(const float* __restrict__ W1, unsigned short* __restrict__ W1t) {
  int idx = blockIdx.x * blockDim.x + threadIdx.x;   // 512*32
  if (idx < 512 * 32) {
    int n = idx >> 5, k = idx & 31;
    float v = (n < 500 && k < 19) ? W1[k * 500 + n] : 0.f;
    W1t[idx] = f2b(v);
  }
}
__global__ void k_prep_w2t(const float* __restrict__ W2, unsigned short* __restrict__ W2t) {
  int idx = blockIdx.x * blockDim.x + threadIdx.x;   // 416*512
  if (idx < 416 * 512) {
    int n = idx >> 9, k = idx & 511;
    float v = (n < 400 && k < 500) ? W2[k * 400 + n] : 0.f;
    W2t[idx] = f2b(v);
  }
}
__global__ void k_prep_w3t(const float* __restrict__ W3, unsigned short* __restrict__ W3t) {
  int idx = blockIdx.x * blockDim.x + threadIdx.x;   // 320*416
  if (idx < 320 * 416) {
    int n = idx / 416, k = idx - n * 416;
    float v = (n < 300 && k < 400) ? W3[k * 300 + n] : 0.f;
    W3t[idx] = f2b(v);
  }
}
__global__ void k_prep_b1(const float* __restrict__ b1, float* __restrict__ b1p) {
  int i = blockIdx.x * blockDim.x + threadIdx.x;
  if (i < 512) b1p[i] = (i < 500) ? b1[i] : 0.f;
}

// ---------------- layer-1 aggregation of x -> bf16 [NNP][32] ----------------
// depth-4 pipelined gather (R4: depth-1 -> latency-bound, HBM 15% peak)
__global__ __launch_bounds__(256) void k_agg_x(
    const float* __restrict__ x, const int* __restrict__ row_ptr,
    const int* __restrict__ csr_src, const float* __restrict__ csr_coef,
    const float* __restrict__ selfc, unsigned short* __restrict__ aggxb, int n) {
  int tid  = threadIdx.x;
  int node = blockIdx.x * 8 + (tid >> 5);
  int lane = tid & 31;
  if (node >= NNP) return;
  float acc = 0.f;
  if (node < n && lane < 19) {
    int e0 = row_ptr[node], e1 = row_ptr[node + 1];
    int cnt = e1 - e0;
    float v0 = 0.f, v1 = 0.f, v2 = 0.f, v3 = 0.f;
    float c0 = 0.f, c1 = 0.f, c2 = 0.f, c3 = 0.f;
    if (cnt > 0) { c0 = csr_coef[e0];     v0 = x[(size_t)csr_src[e0] * 19 + lane]; }
    if (cnt > 1) { c1 = csr_coef[e0 + 1]; v1 = x[(size_t)csr_src[e0 + 1] * 19 + lane]; }
    if (cnt > 2) { c2 = csr_coef[e0 + 2]; v2 = x[(size_t)csr_src[e0 + 2] * 19 + lane]; }
    if (cnt > 3) { c3 = csr_coef[e0 + 3]; v3 = x[(size_t)csr_src[e0 + 3] * 19 + lane]; }
    int e = 0;
    for (; e + 4 <= cnt; e += 4) {
      float tv, tc; int en;
      tv = v0; tc = c0; en = e0 + e + 4;
      if (en < e1) { c0 = csr_coef[en]; v0 = x[(size_t)csr_src[en] * 19 + lane]; }
      acc += tc * tv;
      tv = v1; tc = c1; en = e0 + e + 5;
      if (en < e1) { c1 = csr_coef[en]; v1 = x[(size_t)csr_src[en] * 19 + lane]; }
      acc += tc * tv;
      tv = v2; tc = c2; en = e0 + e + 6;
      if (en < e1) { c2 = csr_coef[en]; v2 = x[(size_t)csr_src[en] * 19 + lane]; }
      acc += tc * tv;
      tv = v3; tc = c3; en = e0 + e + 7;
      if (en < e1) { c3 = csr_coef[en]; v3 = x[(size_t)csr_src[en] * 19 + lane]; }
      acc += tc * tv;
    }
    if (e < cnt) { acc += c0 * v0; e++; }
    if (e < cnt) { acc += c1 * v1; e++; }
    if (e < cnt) { acc += c2 * v2; e++; }
    acc += selfc[node] * x[(size_t)node * 19 + lane];
  }
  aggxb[(size_t)node * 32 + lane] = (node < n && lane < 19) ? f2b(acc) : (unsigned short)0;
}

// ---- fused layer1+2: T2 = (relu(aggx@W1+b1)) @ W2, MFMA, H1 tile in LDS ----
__global__ __launch_bounds__(256) void k_fused12(
    const unsigned short* __restrict__ aggxb, const unsigned short* __restrict__ W1t,
    const float* __restrict__ b1p, const unsigned short* __restrict__ W2t,
    unsigned short* __restrict__ T2) {
  __shared__ unsigned short Hs[32][520];
  int tid = threadIdx.x;
  int lane = tid & 63, wv = tid >> 6;
  int l15 = lane & 15, quad = lane >> 4;
  int r0 = blockIdx.x * 32;
  for (int t = wv; t < 64; t += 4) {
    int rt = t & 1, ct = t >> 1;
    short8 a = *(const short8*)(aggxb + (size_t)(r0 + rt * 16 + l15) * 32 + quad * 8);
    short8 b = *(const short8*)(W1t + (size_t)(ct * 16 + l15) * 32 + quad * 8);
    f32x4 c = {0.f, 0.f, 0.f, 0.f};
    c = mfma_bf16(a, b, c);
    int col = ct * 16 + l15;
    float bias = b1p[col];
    int rbase = rt * 16 + quad * 4;
    #pragma unroll
    for (int r = 0; r < 4; r++)
      Hs[rbase + r][col] = f2b(fmaxf(c[r] + bias, 0.f));
  }
  __syncthreads();
  int rt = wv >> 1, p = wv & 1;
  f32x4 acc[13];
  #pragma unroll
  for (int j = 0; j < 13; j++) acc[j] = (f32x4){0.f, 0.f, 0.f, 0.f};
  for (int k0 = 0; k0 < 512; k0 += 32) {
    short8 a = *(const short8*)&Hs[rt * 16 + l15][k0 + quad * 8];
    #pragma unroll
    for (int j = 0; j < 13; j++) {
      int n = (p + 2 * j) * 16 + l15;
      short8 b = *(const short8*)(W2t + (size_t)n * 512 + k0 + quad * 8);
      acc[j] = mfma_bf16(a, b, acc[j]);
    }
  }
  int rr = r0 + rt * 16 + quad * 4;
  #pragma unroll
  for (int j = 0; j < 13; j++) {
    int n = (p + 2 * j) * 16 + l15;
    if (n < 400) {
      #pragma unroll
      for (int r = 0; r < 4; r++) {
        int row = rr + r;
        if (row < NN) T2[(size_t)row * 400 + n] = f2b(acc[j][r]);
      }
    }
  }
}

// ---- fused layer2 agg + layer3 linear: T3 = relu(agg(T2)+b2) @ W3 (MFMA) ----
// phase A: wave-per-node gather, depth-4 pipelined ring (static slots -> VGPRs)
__global__ __launch_bounds__(256) void k_fused23(
    const unsigned short* __restrict__ T2, const int* __restrict__ row_ptr,
    const int* __restrict__ csr_src, const float* __restrict__ csr_coef,
    const float* __restrict__ selfc, const float* __restrict__ b2,
    const unsigned short* __restrict__ W3t, unsigned short* __restrict__ T3) {
  __shared__ unsigned short Hs[32][424];
  int tid = threadIdx.x;
  int lane = tid & 63, wv = tid >> 6;
  int l15 = lane & 15, quad = lane >> 4;
  int r0 = blockIdx.x * 32;
  bool act = lane < 50;
  int cb = lane * 8;
  for (int i = 0; i < 8; i++) {
    int nl = wv + 4 * i;
    int node = r0 + nl;
    if (node < NN && act) {
      float acc[8];
      #pragma unroll
      for (int j = 0; j < 8; j++) acc[j] = 0.f;
      int e0 = row_ptr[node], e1 = row_ptr[node + 1];
      int cnt = e1 - e0;
      ushort8 v0 = (ushort8)0, v1 = (ushort8)0, v2 = (ushort8)0, v3 = (ushort8)0;
      float c0 = 0.f, c1 = 0.f, c2 = 0.f, c3 = 0.f;
      if (cnt > 0) { c0 = csr_coef[e0];     v0 = *(const ushort8*)(T2 + (size_t)csr_src[e0] * 400 + cb); }
      if (cnt > 1) { c1 = csr_coef[e0 + 1]; v1 = *(const ushort8*)(T2 + (size_t)csr_src[e0 + 1] * 400 + cb); }
      if (cnt > 2) { c2 = csr_coef[e0 + 2]; v2 = *(const ushort8*)(T2 + (size_t)csr_src[e0 + 2] * 400 + cb); }
      if (cnt > 3) { c3 = csr_coef[e0 + 3]; v3 = *(const ushort8*)(T2 + (size_t)csr_src[e0 + 3] * 400 + cb); }
      int e = 0;
      for (; e + 4 <= cnt; e += 4) {
        ushort8 tv; float tc; int en;
        tv = v0; tc = c0; en = e0 + e + 4;
        if (en < e1) { c0 = csr_coef[en]; v0 = *(const ushort8*)(T2 + (size_t)csr_src[en] * 400 + cb); }
        fma8(acc, tc, tv);
        tv = v1; tc = c1; en = e0 + e + 5;
        if (en < e1) { c1 = csr_coef[en]; v1 = *(const ushort8*)(T2 + (size_t)csr_src[en] * 400 + cb); }
        fma8(acc, tc, tv);
        tv = v2; tc = c2; en = e0 + e + 6;
        if (en < e1) { c2 = csr_coef[en]; v2 = *(const ushort8*)(T2 + (size_t)csr_src[en] * 400 + cb); }
        fma8(acc, tc, tv);
        tv = v3; tc = c3; en = e0 + e + 7;
        if (en < e1) { c3 = csr_coef[en]; v3 = *(const ushort8*)(T2 + (size_t)csr_src[en] * 400 + cb); }
        fma8(acc, tc, tv);
      }
      if (e < cnt) { fma8(acc, c0, v0); e++; }
      if (e < cnt) { fma8(acc, c1, v1); e++; }
      if (e < cnt) { fma8(acc, c2, v2); e++; }
      ushort8 sv = *(const ushort8*)(T2 + (size_t)node * 400 + cb);
      float sc = selfc[node];
      ushort8 hv;
      #pragma unroll
      for (int j = 0; j < 8; j++) {
        float val = fmaxf(acc[j] + sc * u2f(sv[j]) + b2[cb + j], 0.f);
        hv[j] = f2b(val);
      }
      *(ushort8*)&Hs[nl][cb] = hv;
    } else if (lane < 52) {
      *(ushort8*)&Hs[nl][cb] = (ushort8)0;
    }
  }
  __syncthreads();
  int rt = wv >> 1, p = wv & 1;
  f32x4 acc[10];
  #pragma unroll
  for (int j = 0; j < 10; j++) acc[j] = (f32x4){0.f, 0.f, 0.f, 0.f};
  for (int k0 = 0; k0 < 416; k0 += 32) {
    short8 a = *(const short8*)&Hs[rt * 16 + l15][k0 + quad * 8];
    #pragma unroll
    for (int j = 0; j < 10; j++) {
      int n = (p + 2 * j) * 16 + l15;
      short8 b = *(const short8*)(W3t + (size_t)n * 416 + k0 + quad * 8);
      acc[j] = mfma_bf16(a, b, acc[j]);
    }
  }
  int rr = r0 + rt * 16 + quad * 4;
  #pragma unroll
  for (int j = 0; j < 10; j++) {
    int n = (p + 2 * j) * 16 + l15;
    if (n < 300) {
      #pragma unroll
      for (int r = 0; r < 4; r++) {
        int row = rr + r;
        if (row < NN) T3[(size_t)row * 304 + n] = f2b(acc[j][r]);
      }
    }
  }
}

// ---- fused layer3 agg + bias + relu + per-graph max pool ----
// batch SORTED -> 4-slot LDS max table; depth-4 pipelined gather.
__global__ __launch_bounds__(256) void k_fused3m(
    const unsigned short* __restrict__ T3, const int* __restrict__ row_ptr,
    const int* __restrict__ csr_src, const float* __restrict__ csr_coef,
    const float* __restrict__ selfc, const float* __restrict__ b3,
    const int* __restrict__ batch, float* __restrict__ gbuf) {
  __shared__ unsigned int lmax[4][304];
  int tid = threadIdx.x;
  int lane = tid & 63, wv = tid >> 6;
  int r0 = blockIdx.x * 32;
  int g0 = batch[r0];
  for (int i = tid; i < 4 * 304; i += 256) ((unsigned int*)lmax)[i] = 0u;
  __syncthreads();
  bool act = lane < 38;
  int cb = lane * 8;
  for (int i = 0; i < 8; i++) {
    int node = r0 + wv * 8 + i;
    if (node >= NN) break;
    if (act) {
      float acc[8];
      #pragma unroll
      for (int j = 0; j < 8; j++) acc[j] = 0.f;
      int e0 = row_ptr[node], e1 = row_ptr[node + 1];
      int cnt = e1 - e0;
      ushort8 v0 = (ushort8)0, v1 = (ushort8)0, v2 = (ushort8)0, v3 = (ushort8)0;
      float c0 = 0.f, c1 = 0.f, c2 = 0.f, c3 = 0.f;
      if (cnt > 0) { c0 = csr_coef[e0];     v0 = *(const ushort8*)(T3 + (size_t)csr_src[e0] * 304 + cb); }
      if (cnt > 1) { c1 = csr_coef[e0 + 1]; v1 = *(const ushort8*)(T3 + (size_t)csr_src[e0 + 1] * 304 + cb); }
      if (cnt > 2) { c2 = csr_coef[e0 + 2]; v2 = *(const ushort8*)(T3 + (size_t)csr_src[e0 + 2] * 304 + cb); }
      if (cnt > 3) { c3 = csr_coef[e0 + 3]; v3 = *(const ushort8*)(T3 + (size_t)csr_src[e0 + 3] * 304 + cb); }
      int e = 0;
      for (; e + 4 <= cnt; e += 4) {
        ushort8 tv; float tc; int en;
        tv = v0; tc = c0; en = e0 + e + 4;
        if (en < e1) { c0 = csr_coef[en]; v0 = *(const ushort8*)(T3 + (size_t)csr_src[en] * 304 + cb); }
        fma8(acc, tc, tv);
        tv = v1; tc = c1; en = e0 + e + 5;
        if (en < e1) { c1 = csr_coef[en]; v1 = *(const ushort8*)(T3 + (size_t)csr_src[en] * 304 + cb); }
        fma8(acc, tc, tv);
        tv = v2; tc = c2; en = e0 + e + 6;
        if (en < e1) { c2 = csr_coef[en]; v2 = *(const ushort8*)(T3 + (size_t)csr_src[en] * 304 + cb); }
        fma8(acc, tc, tv);
        tv = v3; tc = c3; en = e0 + e + 7;
        if (en < e1) { c3 = csr_coef[en]; v3 = *(const ushort8*)(T3 + (size_t)csr_src[en] * 304 + cb); }
        fma8(acc, tc, tv);
      }
      if (e < cnt) { fma8(acc, c0, v0); e++; }
      if (e < cnt) { fma8(acc, c1, v1); e++; }
      if (e < cnt) { fma8(acc, c2, v2); e++; }
      ushort8 sv = *(const ushort8*)(T3 + (size_t)node * 304 + cb);
      float sc = selfc[node];
      int gi = batch[node];
      int slot = gi - g0;
      #pragma unroll
      for (int j = 0; j < 8; j++) {
        int c = cb + j;
        if (c < 300) {
          float v = fmaxf(acc[j] + sc * u2f(sv[j]) + b3[c], 0.f);
          unsigned int uv = __float_as_uint(v);
          if (slot < 4) atomicMax(&lmax[slot][c], uv);
          else atomicMax((unsigned int*)&gbuf[(size_t)gi * 300 + c], uv);
        }
      }
    }
  }
  __syncthreads();
  for (int i = tid; i < 4 * 304; i += 256) {
    int s = i / 304, c = i - s * 304;
    unsigned int uv = lmax[s][c];
    int g = g0 + s;
    if (c < 300 && uv != 0u && g < NG)
      atomicMax((unsigned int*)&gbuf[(size_t)g * 300 + c], uv);
  }
}

// ---------------- small dense head ----------------
__global__ void k_linear(const float* __restrict__ A, const float* __restrict__ W,
                         const float* __restrict__ b, float* __restrict__ C,
                         int M, int N, int K, int relu) {
  int idx = blockIdx.x * blockDim.x + threadIdx.x;
  if (idx >= M * N) return;
  int m = idx / N, n = idx - m * N;
  float acc = b[n];
  for (int k = 0; k < K; k++) acc += A[m * K + k] * W[k * N + n];
  if (relu) acc = fmaxf(acc, 0.f);
  C[idx] = acc;
}

__global__ void k_softmax0(const float* __restrict__ logits, float* __restrict__ out) {
  __shared__ float cmax[6], csum[6];
  int g = threadIdx.x;
  if (g < 6) {
    float m = -1e30f;
    for (int i = 0; i < NG; i++) m = fmaxf(m, logits[i * 6 + g]);
    float s = 0.f;
    for (int i = 0; i < NG; i++) s += expf(logits[i * 6 + g] - m);
    cmax[g] = m; csum[g] = s;
  }
  __syncthreads();
  for (int c = 0; c < 6; c++)
    out[g * 6 + c] = expf(logits[g * 6 + c] - cmax[c]) / csum[c];
}

extern "C" void kernel_launch(void* const* d_in, const int* in_sizes, int n_in,
                              void* d_out, int out_size, void* d_ws, size_t ws_size,
                              hipStream_t stream) {
  const float* x    = (const float*)d_in[0];
  const int*   eidx = (const int*)d_in[1];
  const int*   batch= (const int*)d_in[2];
  const float* W1 = (const float*)d_in[3];  const float* b1 = (const float*)d_in[4];
  const float* W2 = (const float*)d_in[5];  const float* b2 = (const float*)d_in[6];
  const float* W3 = (const float*)d_in[7];  const float* b3 = (const float*)d_in[8];
  const float* Wl1= (const float*)d_in[9];  const float* bl1= (const float*)d_in[10];
  const float* Wl2= (const float*)d_in[11]; const float* bl2= (const float*)d_in[12];
  const float* Wl3= (const float*)d_in[13]; const float* bl3= (const float*)d_in[14];
  const int* srcA = eidx;
  const int* dstA = eidx + NE;

  char* ws = (char*)d_ws;
  size_t off = 0;
  auto alloc = [&](size_t bytes) -> char* {
    char* p = ws + off;
    off = (off + bytes + 255) & ~(size_t)255;
    return p;
  };
  int*   counts  = (int*)  alloc((size_t)NN * 4);
  int*   row_ptr = (int*)  alloc((size_t)(NN + 1) * 4);
  int*   fill    = (int*)  alloc((size_t)NN * 4);
  float* dinv    = (float*)alloc((size_t)NN * 4);
  float* selfc   = (float*)alloc((size_t)NN * 4);
  int*   csr_src = (int*)  alloc((size_t)NE * 4);
  float* csr_coef= (float*)alloc((size_t)NE * 4);
  unsigned short* aggxb = (unsigned short*)alloc((size_t)NNP * 32 * 2);
  unsigned short* W1t   = (unsigned short*)alloc((size_t)512 * 32 * 2);
  unsigned short* W2t   = (unsigned short*)alloc((size_t)416 * 512 * 2);
  unsigned short* W3t   = (unsigned short*)alloc((size_t)320 * 416 * 2);
  float* b1p     = (float*)alloc(512 * 4);
  unsigned short* T2 = (unsigned short*)alloc((size_t)NNP * 400 * 2);
  unsigned short* T3 = (unsigned short*)alloc((size_t)NNP * 304 * 2);
  float* gbuf    = (float*)alloc((size_t)NG * 300 * 4);
  float* a1      = (float*)alloc((size_t)NG * 200 * 4);
  float* a2      = (float*)alloc((size_t)NG * 100 * 4);
  float* logits  = (float*)alloc((size_t)NG * 6 * 4);

  // CSR build
  k_zero_i32<<<(NN + 255) / 256, 256, 0, stream>>>(counts, NN);
  k_count<<<(NE + 255) / 256, 256, 0, stream>>>(dstA, counts, NE);
  k_dinv<<<(NN + 255) / 256, 256, 0, stream>>>(counts, dinv, selfc, NN);
  k_scan<<<1, 1024, 0, stream>>>(counts, row_ptr, fill, NN);
  k_fill<<<(NE + 255) / 256, 256, 0, stream>>>(srcA, dstA, row_ptr, fill, dinv,
                                               csr_src, csr_coef, NE);
  // weight prep
  k_prep_w1t<<<(512 * 32 + 255) / 256, 256, 0, stream>>>(W1, W1t);
  k_prep_w2t<<<(416 * 512 + 255) / 256, 256, 0, stream>>>(W2, W2t);
  k_prep_w3t<<<(320 * 416 + 255) / 256, 256, 0, stream>>>(W3, W3t);
  k_prep_b1<<<2, 256, 0, stream>>>(b1, b1p);
  // layers
  k_agg_x<<<(NNP + 7) / 8, 256, 0, stream>>>(x, row_ptr, csr_src, csr_coef, selfc, aggxb, NN);
  k_fused12<<<NNP / 32, 256, 0, stream>>>(aggxb, W1t, b1p, W2t, T2);
  k_fused23<<<NNP / 32, 256, 0, stream>>>(T2, row_ptr, csr_src, csr_coef, selfc, b2, W3t, T3);
  k_zero_f32<<<(NG * 300 + 255) / 256, 256, 0, stream>>>(gbuf, NG * 300);
  k_fused3m<<<NNP / 32, 256, 0, stream>>>(T3, row_ptr, csr_src, csr_coef, selfc, b3, batch, gbuf);
  // head
  k_linear<<<(NG * 200 + 255) / 256, 256, 0, stream>>>(gbuf, Wl1, bl1, a1, NG, 200, 300, 1);
  k_linear<<<(NG * 100 + 255) / 256, 256, 0, stream>>>(a1, Wl2, bl2, a2, NG, 100, 200, 1);
  k_linear<<<(NG * 6 + 255) / 256, 256, 0, stream>>>(a2, Wl3, bl3, logits, NG, 6, 100, 0);
  k_softmax0<<<1, 256, 0, stream>>>(logits, (float*)d_out);
}